// Round 2
// baseline (663.481 us; speedup 1.0000x reference)
//
#include <hip/hip_runtime.h>

typedef __attribute__((ext_vector_type(8))) short short8;
typedef __attribute__((ext_vector_type(4))) float f32x4;

#define N_TOK 98
#define HD    32
#define NH    4
#define DIM   128
#define C3    384
#define NWIN  64
#define B_TOT 2048
#define MT    112                    // padded token count (7 x 16)
#define SCALE 0.17677669529663687f   // 1/sqrt(32)

// fused LDS layout (bytes):
//   sO  [112][136]s @0      (30464)  -- bf16 attention output, lives whole kernel
//   per-head staging @30464:
//     sQ [112][40]s @30464  (8960), sK [112][40]s @39424 (8960)
//     sP [112][136]s @30464 (30464) -- aliases sQ/sK after QK barrier
//   sVT [32][136]s @60928   (8704)
//   sW  [128][136]s @30464  (34816) -- aliases sP+sVT after head loop
#define SOS    136
#define SQK    40
#define SPS    136
#define SVS    136
#define SWS    136
#define Q_OFF  30464
#define K_OFF  39424
#define VT_OFF 60928
#define LDSZ   69632

__device__ __forceinline__ short f2bf(float f) {       // RNE fp32->bf16
    unsigned u = __builtin_bit_cast(unsigned, f);
    u += 0x7fffu + ((u >> 16) & 1u);
    return (short)(u >> 16);
}

// ---------------------------------------------------------------------------
// biasD[h][i][j] = rpb[rpi[i][j]*4 + h]  (dense, padded to 112x112, once)
// ---------------------------------------------------------------------------
__global__ void bias_kernel(const int* __restrict__ rpi,
                            const float* __restrict__ rpb,
                            float* __restrict__ biasD) {
    int idx = blockIdx.x * 256 + threadIdx.x;
    if (idx >= NH * MT * MT) return;
    int j = idx % MT, rest = idx / MT;
    int i = rest % MT, h = rest / MT;
    float v = 0.f;
    if (i < N_TOK && j < N_TOK) v = rpb[rpi[i * N_TOK + j] * NH + h];
    biasD[idx] = v;
}

// ---------------------------------------------------------------------------
// Fused attention + projection: 1 block per window, 448 thr = 7 waves.
// 4 heads processed sequentially; O accumulates in LDS (bf16); then
// out = O @ W^T + b computed in-block and written directly to global.
// ---------------------------------------------------------------------------
__global__ __launch_bounds__(448) void fused_kernel(
    const float* __restrict__ x, const float* __restrict__ mask,
    const float* __restrict__ biasD, const float* __restrict__ wmat,
    const float* __restrict__ pbias, float* __restrict__ out)
{
    __shared__ __align__(16) char smem[LDSZ];
    short* sO  = (short*)smem;                 // [112][136]
    short* sQ  = (short*)(smem + Q_OFF);       // [112][40]
    short* sK  = (short*)(smem + K_OFF);       // [112][40]
    short* sP  = (short*)(smem + Q_OFF);       // [112][136], aliases sQ/sK
    short* sVT = (short*)(smem + VT_OFF);      // [32][136]
    short* sW  = (short*)(smem + Q_OFF);       // [128][136], aliases sP/sVT

    const int t = threadIdx.x;
    const int b = blockIdx.x;
    const int w = b & (NWIN - 1);
    const float* xb = x + (size_t)b * N_TOK * C3;

    const int lane  = t & 63;
    const int c     = lane & 15, q = lane >> 4;
    const int mtile = t >> 6;                  // 0..6
    const int m0    = mtile * 16;

    // zero sVT token-pad columns once (j = 98..135; never re-garbaged)
    for (int e = t; e < HD * (SVS - N_TOK); e += 448) {
        int d = e / (SVS - N_TOK), j = N_TOK + e % (SVS - N_TOK);
        sVT[d * SVS + j] = 0;
    }

    for (int h = 0; h < NH; ++h) {
        // ---- stage Q (scaled), K as bf16 [token][d]; pad rows 98..111 = 0 ----
        for (int e = t; e < MT * 8; e += 448) {
            int row = e >> 3, d4 = (e & 7) << 2;
            unsigned long long qp = 0ull, kp = 0ull;
            if (row < N_TOK) {
                const float* p = xb + row * C3 + h * HD + d4;
                float4 qv = *(const float4*)p;
                float4 kv = *(const float4*)(p + DIM);
                qp =  (unsigned long long)(unsigned short)f2bf(qv.x * SCALE)
                   | ((unsigned long long)(unsigned short)f2bf(qv.y * SCALE) << 16)
                   | ((unsigned long long)(unsigned short)f2bf(qv.z * SCALE) << 32)
                   | ((unsigned long long)(unsigned short)f2bf(qv.w * SCALE) << 48);
                kp =  (unsigned long long)(unsigned short)f2bf(kv.x)
                   | ((unsigned long long)(unsigned short)f2bf(kv.y) << 16)
                   | ((unsigned long long)(unsigned short)f2bf(kv.z) << 32)
                   | ((unsigned long long)(unsigned short)f2bf(kv.w) << 48);
            }
            *(unsigned long long*)&sQ[row * SQK + d4] = qp;
            *(unsigned long long*)&sK[row * SQK + d4] = kp;
        }
        // ---- stage V transposed: sVT[d][j] ----
        for (int e = t; e < N_TOK * 8; e += 448) {
            int j = e >> 3, d4 = (e & 7) << 2;
            float4 vv = *(const float4*)(xb + j * C3 + 2 * DIM + h * HD + d4);
            sVT[(d4 + 0) * SVS + j] = f2bf(vv.x);
            sVT[(d4 + 1) * SVS + j] = f2bf(vv.y);
            sVT[(d4 + 2) * SVS + j] = f2bf(vv.z);
            sVT[(d4 + 3) * SVS + j] = f2bf(vv.w);
        }
        __syncthreads();   // staging done (also orders sVT pad-zeroing on h=0)

        // ---- S = Q K^T : 7 MFMAs ----
        short8 afrag = *(const short8*)&sQ[(m0 + c) * SQK + q * 8];
        f32x4 acc[7];
        #pragma unroll
        for (int nt = 0; nt < 7; ++nt) {
            f32x4 z = {0.f, 0.f, 0.f, 0.f};
            short8 bfrag = *(const short8*)&sK[(nt * 16 + c) * SQK + q * 8];
            acc[nt] = __builtin_amdgcn_mfma_f32_16x16x32_bf16(afrag, bfrag, z, 0, 0, 0);
        }
        __syncthreads();   // everyone done reading sQ/sK; sP may now overwrite

        // ---- bias + mask + register softmax (rows = q*4+r of this M-tile) ----
        float S[7][4];
        float mx[4] = {-1e30f, -1e30f, -1e30f, -1e30f};
        #pragma unroll
        for (int nt = 0; nt < 7; ++nt) {
            int j = nt * 16 + c;
            #pragma unroll
            for (int r = 0; r < 4; ++r) {
                int i = m0 + q * 4 + r;
                float v = acc[nt][r] + biasD[(h * MT + i) * MT + j];
                if (j < N_TOK && i < N_TOK)
                    v += mask[((size_t)w * N_TOK + i) * N_TOK + j];
                if (j >= N_TOK) v = -1e30f;
                S[nt][r] = v;
                mx[r] = fmaxf(mx[r], v);
            }
        }
        #pragma unroll
        for (int r = 0; r < 4; ++r) {
            float m = mx[r];
            m = fmaxf(m, __shfl_xor(m, 1));
            m = fmaxf(m, __shfl_xor(m, 2));
            m = fmaxf(m, __shfl_xor(m, 4));
            m = fmaxf(m, __shfl_xor(m, 8));
            mx[r] = m;
        }
        float sm[4] = {0.f, 0.f, 0.f, 0.f};
        #pragma unroll
        for (int nt = 0; nt < 7; ++nt)
            #pragma unroll
            for (int r = 0; r < 4; ++r) {
                float e = (S[nt][r] > -1e29f) ? __expf(S[nt][r] - mx[r]) : 0.f;
                S[nt][r] = e;
                sm[r] += e;
            }
        float inv[4];
        #pragma unroll
        for (int r = 0; r < 4; ++r) {
            float s = sm[r];
            s += __shfl_xor(s, 1);
            s += __shfl_xor(s, 2);
            s += __shfl_xor(s, 4);
            s += __shfl_xor(s, 8);
            inv[r] = 1.0f / s;   // normalization applied at O write
        }

        // ---- write P (unnormalized, bf16) to own rows of sP ----
        #pragma unroll
        for (int nt = 0; nt < 7; ++nt)
            #pragma unroll
            for (int r = 0; r < 4; ++r)
                sP[(m0 + q * 4 + r) * SPS + nt * 16 + c] = f2bf(S[nt][r]);
        // zero k-pad cols 112..127 of own rows (lane: row m0+c, 4 cols)
        #pragma unroll
        for (int kk = 0; kk < 4; ++kk)
            sP[(m0 + c) * SPS + 112 + q * 4 + kk] = 0;

        // ---- O = P V : 4 K-tiles x 2 N-tiles (reads own rows only) ----
        f32x4 oacc[2] = {{0.f,0.f,0.f,0.f}, {0.f,0.f,0.f,0.f}};
        #pragma unroll
        for (int kt = 0; kt < 4; ++kt) {
            short8 pa = *(const short8*)&sP[(m0 + c) * SPS + kt * 32 + q * 8];
            #pragma unroll
            for (int n2 = 0; n2 < 2; ++n2) {
                short8 vb = *(const short8*)&sVT[(n2 * 16 + c) * SVS + kt * 32 + q * 8];
                oacc[n2] = __builtin_amdgcn_mfma_f32_16x16x32_bf16(pa, vb, oacc[n2], 0, 0, 0);
            }
        }
        // ---- write normalized O (bf16) into sO columns of this head ----
        #pragma unroll
        for (int n2 = 0; n2 < 2; ++n2)
            #pragma unroll
            for (int r = 0; r < 4; ++r)
                sO[(m0 + q * 4 + r) * SOS + h * HD + n2 * 16 + c]
                    = f2bf(oacc[n2][r] * inv[r]);
        __syncthreads();   // PV done reading sP/sVT; next head may restage
    }

    // ---- stage W bf16 into dead staging region ----
    for (int e = t; e < DIM * 32; e += 448) {
        int rr = e >> 5, k4 = (e & 31) << 2;
        float4 v = *(const float4*)&wmat[rr * DIM + k4];
        sW[rr * SWS + k4 + 0] = f2bf(v.x);
        sW[rr * SWS + k4 + 1] = f2bf(v.y);
        sW[rr * SWS + k4 + 2] = f2bf(v.z);
        sW[rr * SWS + k4 + 3] = f2bf(v.w);
    }
    __syncthreads();

    // ---- out = O @ W^T + b : 4 K-tiles x 8 N-tiles, write direct to global ----
    float bcol[8];
    #pragma unroll
    for (int nt = 0; nt < 8; ++nt) bcol[nt] = pbias[nt * 16 + c];

    f32x4 pacc[8];
    #pragma unroll
    for (int nt = 0; nt < 8; ++nt) pacc[nt] = (f32x4){0.f, 0.f, 0.f, 0.f};

    #pragma unroll
    for (int kt = 0; kt < 4; ++kt) {
        short8 a = *(const short8*)&sO[(m0 + c) * SOS + kt * 32 + q * 8];
        #pragma unroll
        for (int nt = 0; nt < 8; ++nt) {
            short8 bb = *(const short8*)&sW[(nt * 16 + c) * SWS + kt * 32 + q * 8];
            pacc[nt] = __builtin_amdgcn_mfma_f32_16x16x32_bf16(a, bb, pacc[nt], 0, 0, 0);
        }
    }
    #pragma unroll
    for (int nt = 0; nt < 8; ++nt)
        #pragma unroll
        for (int r = 0; r < 4; ++r) {
            int i = m0 + q * 4 + r;
            if (i < N_TOK)
                out[((size_t)b * N_TOK + i) * DIM + nt * 16 + c]
                    = pacc[nt][r] + bcol[nt];
        }
}

extern "C" void kernel_launch(void* const* d_in, const int* in_sizes, int n_in,
                              void* d_out, int out_size, void* d_ws, size_t ws_size,
                              hipStream_t stream) {
    const float* x    = (const float*)d_in[0];
    const int*   rpi  = (const int*)  d_in[1];
    const float* mask = (const float*)d_in[2];
    const float* rpb  = (const float*)d_in[3];
    const float* pw   = (const float*)d_in[4];
    const float* pb   = (const float*)d_in[5];
    float* out   = (float*)d_out;
    float* biasD = (float*)d_ws;     // 4*112*112*4 = 200704 B

    bias_kernel<<<(NH * MT * MT + 255) / 256, 256, 0, stream>>>(rpi, rpb, biasD);
    fused_kernel<<<B_TOT, 448, 0, stream>>>(x, mask, biasD, pw, pb, out);
}